// Round 9
// baseline (230.176 us; speedup 1.0000x reference)
//
#include <hip/hip_runtime.h>
#include <hip/hip_bf16.h>

// Problem constants (from reference)
#define LL 2000
#define MM 3
#define FF 512
#define NN (MM * LL)          // 6000 nodes
#define NUM_LAYERS 2
#define CAP 128               // bucket capacity; deg ~ N(66.7, 8.2) -> P(any>128) ~ 1e-9

typedef __attribute__((ext_vector_type(8))) short bf16x8;
typedef __attribute__((ext_vector_type(4))) float f32x4;

__device__ __forceinline__ unsigned short f2bf(float x) {
    __hip_bfloat16 b = __float2bfloat16(x);
    return *(unsigned short*)&b;
}

// async global->LDS, 16B per lane. lds dest is wave-uniform base + lane*16.
__device__ __forceinline__ void gload16(const void* gsrc, void* ldst) {
    __builtin_amdgcn_global_load_lds((const __attribute__((address_space(1))) unsigned int*)gsrc,
                                     (__attribute__((address_space(3))) unsigned int*)ldst,
                                     16, 0, 0);
}

// ---------------------------------------------------------------------------
// Fused prep: block-range dispatch.
//  [0, 3000):     concat [x_a;x_v;x_t] -> feat bf16, out fp32 init
//  [3000, 3256):  weight transpose+cvt, slots: 0=gW0^T 1=fW0^T 2=gW1^T 3=fW1^T
// ---------------------------------------------------------------------------
__global__ __launch_bounds__(256) void prep(const float* __restrict__ xa,
                                            const float* __restrict__ xv,
                                            const float* __restrict__ xt,
                                            unsigned short* __restrict__ feat,
                                            float* __restrict__ out_sum,
                                            const float* __restrict__ gcnW,
                                            const float* __restrict__ fcW,
                                            unsigned short* __restrict__ Wt) {
    __shared__ unsigned short tile[64][65];
    int b = blockIdx.x;
    int tid = threadIdx.x;
    if (b < 3000) {
        // ----- concat -----
        int idx4 = b * 256 + tid;
        const int per4 = (LL * FF) / 4;
        const float4* src;
        int off;
        if (idx4 < per4)            { src = (const float4*)xa; off = idx4; }
        else if (idx4 < 2 * per4)   { src = (const float4*)xv; off = idx4 - per4; }
        else                        { src = (const float4*)xt; off = idx4 - 2 * per4; }
        float4 v = src[off];
        ((float4*)out_sum)[idx4] = v;
        ushort4 pk;
        pk.x = f2bf(v.x); pk.y = f2bf(v.y); pk.z = f2bf(v.z); pk.w = f2bf(v.w);
        ((ushort4*)feat)[idx4] = pk;
    } else {
        // ----- wtrans -----
        int idx = b - 3000;
        int mz = idx >> 6;          // 0,1 gcn ; 2,3 fc
        int rem = idx & 63;
        int k0 = (rem >> 3) * 64;
        int n0 = (rem & 7) * 64;
        int layer = (mz < 2) ? mz : mz - 2;
        const float* src = (mz < 2) ? (gcnW + (size_t)layer * FF * FF)
                                    : (fcW + (size_t)layer * FF * FF);
        int slot = (mz < 2) ? (mz * 2) : ((mz - 2) * 2 + 1);
        unsigned short* dst = Wt + (size_t)slot * FF * FF;
        for (int i = tid; i < 64 * 64; i += 256) {
            int r = i >> 6, c = i & 63;
            tile[r][c] = f2bf(src[(size_t)(k0 + r) * FF + n0 + c]);
        }
        __syncthreads();
        for (int i = tid; i < 64 * 64; i += 256) {
            int r = i >> 6, c = i & 63;
            dst[(size_t)(n0 + r) * FF + k0 + c] = tile[c][r];
        }
    }
}

// ---------------------------------------------------------------------------
// Merged dispatch: gemm0 blocks [0, ngemm) + scatter blocks [ngemm, ...).
// Both depend only on prep (+memset). gemm0: H = feat @ gW0 (64x64 tile).
// scatter (one pass, cursor atomic): slot = cursor[r]++;
//   bucket[r*CAP+slot] = {col, bits(w)}; row_sum[r] += w.
// Atomic latency hides under the co-resident MFMA blocks.
// ---------------------------------------------------------------------------
__global__ __launch_bounds__(256) void gemm0_scatter(const unsigned short* __restrict__ A,
                                                     const unsigned short* __restrict__ Bt,
                                                     unsigned short* __restrict__ Hout,
                                                     int M, int gxm, int ngemm,
                                                     const int* __restrict__ esrc,
                                                     const int* __restrict__ edst,
                                                     const float* __restrict__ ew,
                                                     int* __restrict__ cursor,
                                                     float* __restrict__ row_sum,
                                                     int2* __restrict__ bucket, int E) {
    __shared__ short As[64 * 64];
    __shared__ short Bs[64 * 64];
    int b = blockIdx.x;
    int tid = threadIdx.x;
    if (b >= ngemm) {
        // ----- scatter -----
        int e = (b - ngemm) * 256 + tid;
        if (e < E) {
            int r = esrc[e];
            float w = ew[e];
            int slot = atomicAdd(&cursor[r], 1);
            atomicAdd(&row_sum[r], w);
            if (slot < CAP) {
                int2 p;
                p.x = edst[e];
                p.y = __float_as_int(w);
                bucket[(size_t)r * CAP + slot] = p;
            }
        }
        return;
    }
    // ----- gemm0 -----
    int wave = tid >> 6;
    int lane = tid & 63;
    int lane16 = lane & 15;
    int quad = lane >> 4;
    int m0 = (b % gxm) * 64;
    int n0 = (b / gxm) * 64;
    int wm = (wave >> 1) * 32;
    int wn = (wave & 1) * 32;

    f32x4 acc[2][2] = {};

    for (int k0 = 0; k0 < FF; k0 += 64) {
#pragma unroll
        for (int s = 0; s < 2; s++) {
            int c = wave * 128 + s * 64 + lane;
            int row = c >> 3;
            int kc = (c & 7) ^ (row & 7);
            int ar = m0 + row; if (ar >= M) ar = M - 1;
            gload16((const short*)A + (size_t)ar * FF + k0 + kc * 8,
                    &As[(wave * 128 + s * 64) * 8]);
            gload16((const short*)Bt + (size_t)(n0 + row) * FF + k0 + kc * 8,
                    &Bs[(wave * 128 + s * 64) * 8]);
        }
        __syncthreads();
#pragma unroll
        for (int kk = 0; kk < 2; kk++) {
            bf16x8 a[2], bb[2];
#pragma unroll
            for (int mt = 0; mt < 2; mt++) {
                int row = wm + mt * 16 + lane16;
                int kc = (kk * 4 + quad) ^ (row & 7);
                a[mt] = *(const bf16x8*)&As[row * 64 + kc * 8];
            }
#pragma unroll
            for (int nt = 0; nt < 2; nt++) {
                int row = wn + nt * 16 + lane16;
                int kc = (kk * 4 + quad) ^ (row & 7);
                bb[nt] = *(const bf16x8*)&Bs[row * 64 + kc * 8];
            }
#pragma unroll
            for (int mt = 0; mt < 2; mt++)
#pragma unroll
                for (int nt = 0; nt < 2; nt++)
                    acc[mt][nt] = __builtin_amdgcn_mfma_f32_16x16x32_bf16(a[mt], bb[nt], acc[mt][nt], 0, 0, 0);
        }
        __syncthreads();
    }

#pragma unroll
    for (int mt = 0; mt < 2; mt++) {
#pragma unroll
        for (int nt = 0; nt < 2; nt++) {
            int n = n0 + wn + nt * 16 + lane16;
#pragma unroll
            for (int rr = 0; rr < 4; rr++) {
                int m = m0 + wm + mt * 16 + quad * 4 + rr;
                if (m < M) Hout[(size_t)m * FF + n] = f2bf(acc[mt][nt][rr]);
            }
        }
    }
}

// ---------------------------------------------------------------------------
// dinv[i] = row_sum[i] > 0 ? rsqrt(row_sum[i]) : 0   (24 KB read — trivial)
// ---------------------------------------------------------------------------
__global__ void dinv_kernel(const float* __restrict__ row_sum,
                            float* __restrict__ dinv, int n) {
    int i = blockIdx.x * blockDim.x + threadIdx.x;
    if (i >= n) return;
    float s = row_sum[i];
    dinv[i] = (s > 0.0f) ? rsqrtf(s) : 0.0f;
}

// ---------------------------------------------------------------------------
// SpMM gather over buckets:
//   feat[r,:] = relu( dinv[r] * sum_e (w_e*dinv[c_e]) * H[c_e,:] + bias )
// One WAVE per row; lane covers 8 features (16B dwordx4 -> full 1KB H row per
// wave-load). Unroll-4 + software-pipelined bucket prefetch. dinv[c] is a
// wave-uniform load from a 24KB cache-resident table.
// ---------------------------------------------------------------------------
__device__ __forceinline__ void accum8(float* acc, uint4 h, float v) {
    unsigned int d[4] = {h.x, h.y, h.z, h.w};
#pragma unroll
    for (int k = 0; k < 4; k++) {
        float lo = __uint_as_float(d[k] << 16);
        float hi = __uint_as_float(d[k] & 0xFFFF0000u);
        acc[2 * k]     = fmaf(v, lo, acc[2 * k]);
        acc[2 * k + 1] = fmaf(v, hi, acc[2 * k + 1]);
    }
}

__global__ __launch_bounds__(256) void spmm_bias_relu(const unsigned short* __restrict__ H,
                                                      const int* __restrict__ counts,
                                                      const int2* __restrict__ bucket,
                                                      const float* __restrict__ dinv,
                                                      const float* __restrict__ bias,
                                                      unsigned short* __restrict__ featOut) {
    int wave = threadIdx.x >> 6, lane = threadIdx.x & 63;
    int r = blockIdx.x * 4 + wave;
    int s = r * CAP;
    int e = s + min(counts[r], CAP);
    int f0 = lane * 8;
    const unsigned short* Hf = H + f0;
    float acc[8] = {0, 0, 0, 0, 0, 0, 0, 0};

    int i = s;
    int2 p0, p1, p2, p3;
    bool have = (i + 4 <= e);
    if (have) { p0 = bucket[i]; p1 = bucket[i + 1]; p2 = bucket[i + 2]; p3 = bucket[i + 3]; }
    while (have) {
        uint4 a0 = *(const uint4*)(Hf + (size_t)p0.x * FF);
        uint4 a1 = *(const uint4*)(Hf + (size_t)p1.x * FF);
        uint4 a2 = *(const uint4*)(Hf + (size_t)p2.x * FF);
        uint4 a3 = *(const uint4*)(Hf + (size_t)p3.x * FF);
        float v0 = __int_as_float(p0.y) * dinv[p0.x];
        float v1 = __int_as_float(p1.y) * dinv[p1.x];
        float v2 = __int_as_float(p2.y) * dinv[p2.x];
        float v3 = __int_as_float(p3.y) * dinv[p3.x];
        i += 4;
        have = (i + 4 <= e);
        if (have) { p0 = bucket[i]; p1 = bucket[i + 1]; p2 = bucket[i + 2]; p3 = bucket[i + 3]; }
        accum8(acc, a0, v0);
        accum8(acc, a1, v1);
        accum8(acc, a2, v2);
        accum8(acc, a3, v3);
    }
    for (; i < e; i++) {
        int2 p = bucket[i];
        uint4 a = *(const uint4*)(Hf + (size_t)p.x * FF);
        accum8(acc, a, __int_as_float(p.y) * dinv[p.x]);
    }

    float dr = dinv[r];
    float4 b0 = *(const float4*)(bias + f0);
    float4 b1 = *(const float4*)(bias + f0 + 4);
    float bb[8] = {b0.x, b0.y, b0.z, b0.w, b1.x, b1.y, b1.z, b1.w};
    unsigned int o[4];
#pragma unroll
    for (int k = 0; k < 4; k++) {
        float v0 = fmaxf(fmaf(acc[2 * k], dr, bb[2 * k]), 0.0f);
        float v1 = fmaxf(fmaf(acc[2 * k + 1], dr, bb[2 * k + 1]), 0.0f);
        o[k] = (unsigned int)f2bf(v0) | ((unsigned int)f2bf(v1) << 16);
    }
    uint4 ov; ov.x = o[0]; ov.y = o[1]; ov.z = o[2]; ov.w = o[3];
    *(uint4*)(featOut + (size_t)r * FF + f0) = ov;
}

// ---------------------------------------------------------------------------
// MFMA GEMM over stacked transposed weights Bt[n][k]. 64x64 tile, BK=64,
// 256 threads = 4 waves (2x2 of 32x32), XOR-swizzled LDS.
// MODE 1: all cols -> out += leaky_relu(v + fbias[n]), grid.y = 8
// MODE 2: n0<512 -> out += leaky_relu(v + fbias[n]); n0>=512 -> H store at
//         n-512, grid.y = 16 (Bt = [fW_i^T ; gW_{i+1}^T], same input feat)
// ---------------------------------------------------------------------------
template <int MODE>
__global__ __launch_bounds__(256) void gemm_bf16(const unsigned short* __restrict__ A,
                                                 const unsigned short* __restrict__ Bt,
                                                 const float* __restrict__ fbias,
                                                 unsigned short* __restrict__ Hout,
                                                 float* __restrict__ out,
                                                 int M) {
    __shared__ short As[64 * 64];
    __shared__ short Bs[64 * 64];
    int tid = threadIdx.x;
    int wave = tid >> 6;
    int lane = tid & 63;
    int lane16 = lane & 15;
    int quad = lane >> 4;
    int m0 = blockIdx.x * 64;
    int n0 = blockIdx.y * 64;
    int wm = (wave >> 1) * 32;
    int wn = (wave & 1) * 32;

    f32x4 acc[2][2] = {};

    for (int k0 = 0; k0 < FF; k0 += 64) {
#pragma unroll
        for (int s = 0; s < 2; s++) {
            int c = wave * 128 + s * 64 + lane;
            int row = c >> 3;
            int kc = (c & 7) ^ (row & 7);
            int ar = m0 + row; if (ar >= M) ar = M - 1;
            gload16((const short*)A + (size_t)ar * FF + k0 + kc * 8,
                    &As[(wave * 128 + s * 64) * 8]);
            gload16((const short*)Bt + (size_t)(n0 + row) * FF + k0 + kc * 8,
                    &Bs[(wave * 128 + s * 64) * 8]);
        }
        __syncthreads();
#pragma unroll
        for (int kk = 0; kk < 2; kk++) {
            bf16x8 a[2], bb[2];
#pragma unroll
            for (int mt = 0; mt < 2; mt++) {
                int row = wm + mt * 16 + lane16;
                int kc = (kk * 4 + quad) ^ (row & 7);
                a[mt] = *(const bf16x8*)&As[row * 64 + kc * 8];
            }
#pragma unroll
            for (int nt = 0; nt < 2; nt++) {
                int row = wn + nt * 16 + lane16;
                int kc = (kk * 4 + quad) ^ (row & 7);
                bb[nt] = *(const bf16x8*)&Bs[row * 64 + kc * 8];
            }
#pragma unroll
            for (int mt = 0; mt < 2; mt++)
#pragma unroll
                for (int nt = 0; nt < 2; nt++)
                    acc[mt][nt] = __builtin_amdgcn_mfma_f32_16x16x32_bf16(a[mt], bb[nt], acc[mt][nt], 0, 0, 0);
        }
        __syncthreads();
    }

    bool isFc = (MODE == 1) || (MODE == 2 && n0 < FF);
#pragma unroll
    for (int mt = 0; mt < 2; mt++) {
#pragma unroll
        for (int nt = 0; nt < 2; nt++) {
            int n = n0 + wn + nt * 16 + lane16;
            float bv = isFc ? fbias[n] : 0.0f;
#pragma unroll
            for (int rr = 0; rr < 4; rr++) {
                int m = m0 + wm + mt * 16 + quad * 4 + rr;
                if (m < M) {
                    float v = acc[mt][nt][rr];
                    if (isFc) {
                        v += bv;
                        v = (v > 0.0f) ? v : 0.01f * v;
                        out[(size_t)m * FF + n] += v;
                    } else {
                        Hout[(size_t)m * FF + (n - FF)] = f2bf(v);
                    }
                }
            }
        }
    }
}

// ---------------------------------------------------------------------------
extern "C" void kernel_launch(void* const* d_in, const int* in_sizes, int n_in,
                              void* d_out, int out_size, void* d_ws, size_t ws_size,
                              hipStream_t stream) {
    const float* xa      = (const float*)d_in[0];
    const float* xv      = (const float*)d_in[1];
    const float* xt      = (const float*)d_in[2];
    const float* ew      = (const float*)d_in[3];
    const float* gcn_W   = (const float*)d_in[4];
    const float* gcn_b   = (const float*)d_in[5];
    const float* fc_W    = (const float*)d_in[6];
    const float* fc_b    = (const float*)d_in[7];
    const int*   eidx    = (const int*)d_in[8];
    const int E = in_sizes[8] / 2;
    const int* esrc = eidx;
    const int* edst = eidx + E;

    float* out = (float*)d_out;

    // workspace layout (64B aligned blocks)
    char* w = (char*)d_ws;
    int*   cursor  = (int*)  (w + 0);            // 24000 B (pad 24064)
    float* row_sum = (float*)(w + 24064);        // 24000 B (pad to 48128)
    float* dinv    = (float*)(w + 48128);        // 24000 B (pad to 72192)
    int2*  bucket  = (int2*) (w + 72192);        // 6000*CAP*8 = 6,144,000 B
    unsigned short* feat = (unsigned short*)(w + 6216192);    // 6,144,000 B
    unsigned short* H    = (unsigned short*)(w + 12360192);   // 6,144,000 B
    unsigned short* Wt   = (unsigned short*)(w + 18504192);   // 2,097,152 B

    // zero cursor + row_sum (contiguous 48,064 B)
    hipMemsetAsync(w, 0, 48064, stream);

    const int eblocks = (E + 255) / 256;
    prep<<<3256, 256, 0, stream>>>(xa, xv, xt, feat, out, gcn_W, fc_W, Wt);

    const int gxm = (NN + 63) / 64;   // 94
    const int ngemm0 = gxm * 8;       // 752
    // Wt slots: 0=gW0^T, 1=fW0^T, 2=gW1^T, 3=fW1^T (slots 1,2 contiguous)
    // merged: H0 = feat0 @ gW0  ||  one-pass cursor scatter (independent)
    gemm0_scatter<<<ngemm0 + eblocks, 256, 0, stream>>>(feat, Wt, H, NN, gxm, ngemm0,
                                                        esrc, edst, ew, cursor, row_sum,
                                                        bucket, E);
    dinv_kernel<<<(NN + 255) / 256, 256, 0, stream>>>(row_sum, dinv, NN);

    // feat1 = relu(gcn@H0 + gb0)
    spmm_bias_relu<<<NN / 4, 256, 0, stream>>>(H, cursor, bucket, dinv, gcn_b, feat);
    // out += leaky(feat1@fW0 + fb0)  AND  H1 = feat1 @ gW1   (fused)
    gemm_bf16<2><<<dim3(gxm, 16), 256, 0, stream>>>(feat, Wt + (size_t)FF * FF, fc_b, H, out, NN);
    // feat2 = relu(gcn@H1 + gb1)
    spmm_bias_relu<<<NN / 4, 256, 0, stream>>>(H, cursor, bucket, dinv, gcn_b + FF, feat);
    // out += leaky(feat2@fW1 + fb1)
    gemm_bf16<1><<<dim3(gxm, 8), 256, 0, stream>>>(feat, Wt + (size_t)3 * FF * FF, fc_b + FF, nullptr, out, NN);
}

// Round 10
// 219.086 us; speedup vs baseline: 1.0506x; 1.0506x over previous
//
#include <hip/hip_runtime.h>
#include <hip/hip_bf16.h>

// Problem constants (from reference)
#define LL 2000
#define MM 3
#define FF 512
#define NN (MM * LL)          // 6000 nodes
#define NUM_LAYERS 2
#define CAP 128               // bucket capacity; deg ~ N(66.7, 8.2) -> P(any>128) ~ 1e-9

typedef __attribute__((ext_vector_type(8))) short bf16x8;
typedef __attribute__((ext_vector_type(4))) float f32x4;

__device__ __forceinline__ unsigned short f2bf(float x) {
    __hip_bfloat16 b = __float2bfloat16(x);
    return *(unsigned short*)&b;
}

// async global->LDS, 16B per lane. lds dest is wave-uniform base + lane*16.
__device__ __forceinline__ void gload16(const void* gsrc, void* ldst) {
    __builtin_amdgcn_global_load_lds((const __attribute__((address_space(1))) unsigned int*)gsrc,
                                     (__attribute__((address_space(3))) unsigned int*)ldst,
                                     16, 0, 0);
}

// ---------------------------------------------------------------------------
// Fused prep: block-range dispatch.
//  [0, 3000):     concat [x_a;x_v;x_t] -> featA bf16, out fp32 init
//  [3000, 3256):  weight transpose+cvt, slots: 0=gW0^T 1=fW0^T 2=gW1^T 3=fW1^T
//  [3256, ...):   edge histogram: pir[e] = rank of edge e within its row
//                 (single atomic/edge; overlaps with the streaming concat)
// ---------------------------------------------------------------------------
__global__ __launch_bounds__(256) void prep(const float* __restrict__ xa,
                                            const float* __restrict__ xv,
                                            const float* __restrict__ xt,
                                            unsigned short* __restrict__ feat,
                                            float* __restrict__ out_sum,
                                            const float* __restrict__ gcnW,
                                            const float* __restrict__ fcW,
                                            unsigned short* __restrict__ Wt,
                                            const int* __restrict__ esrc,
                                            int* __restrict__ counts,
                                            int* __restrict__ pir, int E) {
    __shared__ unsigned short tile[64][65];
    int b = blockIdx.x;
    int tid = threadIdx.x;
    if (b < 3000) {
        // ----- concat -----
        int idx4 = b * 256 + tid;
        const int per4 = (LL * FF) / 4;
        const float4* src;
        int off;
        if (idx4 < per4)            { src = (const float4*)xa; off = idx4; }
        else if (idx4 < 2 * per4)   { src = (const float4*)xv; off = idx4 - per4; }
        else                        { src = (const float4*)xt; off = idx4 - 2 * per4; }
        float4 v = src[off];
        ((float4*)out_sum)[idx4] = v;
        ushort4 pk;
        pk.x = f2bf(v.x); pk.y = f2bf(v.y); pk.z = f2bf(v.z); pk.w = f2bf(v.w);
        ((ushort4*)feat)[idx4] = pk;
    } else if (b < 3256) {
        // ----- wtrans -----
        int idx = b - 3000;
        int mz = idx >> 6;          // 0,1 gcn ; 2,3 fc
        int rem = idx & 63;
        int k0 = (rem >> 3) * 64;
        int n0 = (rem & 7) * 64;
        int layer = (mz < 2) ? mz : mz - 2;
        const float* src = (mz < 2) ? (gcnW + (size_t)layer * FF * FF)
                                    : (fcW + (size_t)layer * FF * FF);
        int slot = (mz < 2) ? (mz * 2) : ((mz - 2) * 2 + 1);
        unsigned short* dst = Wt + (size_t)slot * FF * FF;
        for (int i = tid; i < 64 * 64; i += 256) {
            int r = i >> 6, c = i & 63;
            tile[r][c] = f2bf(src[(size_t)(k0 + r) * FF + n0 + c]);
        }
        __syncthreads();
        for (int i = tid; i < 64 * 64; i += 256) {
            int r = i >> 6, c = i & 63;
            dst[(size_t)(n0 + r) * FF + k0 + c] = tile[c][r];
        }
    } else {
        // ----- edge histogram -----
        int e = (b - 3256) * 256 + tid;
        if (e < E) pir[e] = atomicAdd(&counts[esrc[e]], 1);
    }
}

// ---------------------------------------------------------------------------
// Merged dispatch: scatter blocks [0, sblk) + gemm0 blocks [sblk, ...).
// Scatter first: long-latency random stores start earliest, hide under MFMA.
// scatter (atomic-free): bucket[r*CAP + pir[e]] = {col, bits(w)}
// gemm0: H = featA @ gW0 (64x64 tile, store bf16).
// ---------------------------------------------------------------------------
__global__ __launch_bounds__(256) void gemm0_scatter(const unsigned short* __restrict__ A,
                                                     const unsigned short* __restrict__ Bt,
                                                     unsigned short* __restrict__ Hout,
                                                     int M, int gxm, int sblk,
                                                     const int* __restrict__ esrc,
                                                     const int* __restrict__ edst,
                                                     const float* __restrict__ ew,
                                                     const int* __restrict__ pir,
                                                     int2* __restrict__ bucket, int E) {
    __shared__ short As[64 * 64];
    __shared__ short Bs[64 * 64];
    int b = blockIdx.x;
    int tid = threadIdx.x;
    if (b < sblk) {
        // ----- scatter -----
        int e = b * 256 + tid;
        if (e < E) {
            int r = esrc[e];
            int slot = pir[e];
            if (slot < CAP) {
                int2 p;
                p.x = edst[e];
                p.y = __float_as_int(ew[e]);
                bucket[(size_t)r * CAP + slot] = p;
            }
        }
        return;
    }
    // ----- gemm0 -----
    int bg = b - sblk;
    int wave = tid >> 6;
    int lane = tid & 63;
    int lane16 = lane & 15;
    int quad = lane >> 4;
    int m0 = (bg % gxm) * 64;
    int n0 = (bg / gxm) * 64;
    int wm = (wave >> 1) * 32;
    int wn = (wave & 1) * 32;

    f32x4 acc[2][2] = {};

    for (int k0 = 0; k0 < FF; k0 += 64) {
#pragma unroll
        for (int s = 0; s < 2; s++) {
            int c = wave * 128 + s * 64 + lane;
            int row = c >> 3;
            int kc = (c & 7) ^ (row & 7);
            int ar = m0 + row; if (ar >= M) ar = M - 1;
            gload16((const short*)A + (size_t)ar * FF + k0 + kc * 8,
                    &As[(wave * 128 + s * 64) * 8]);
            gload16((const short*)Bt + (size_t)(n0 + row) * FF + k0 + kc * 8,
                    &Bs[(wave * 128 + s * 64) * 8]);
        }
        __syncthreads();
#pragma unroll
        for (int kk = 0; kk < 2; kk++) {
            bf16x8 a[2], bb[2];
#pragma unroll
            for (int mt = 0; mt < 2; mt++) {
                int row = wm + mt * 16 + lane16;
                int kc = (kk * 4 + quad) ^ (row & 7);
                a[mt] = *(const bf16x8*)&As[row * 64 + kc * 8];
            }
#pragma unroll
            for (int nt = 0; nt < 2; nt++) {
                int row = wn + nt * 16 + lane16;
                int kc = (kk * 4 + quad) ^ (row & 7);
                bb[nt] = *(const bf16x8*)&Bs[row * 64 + kc * 8];
            }
#pragma unroll
            for (int mt = 0; mt < 2; mt++)
#pragma unroll
                for (int nt = 0; nt < 2; nt++)
                    acc[mt][nt] = __builtin_amdgcn_mfma_f32_16x16x32_bf16(a[mt], bb[nt], acc[mt][nt], 0, 0, 0);
        }
        __syncthreads();
    }

#pragma unroll
    for (int mt = 0; mt < 2; mt++) {
#pragma unroll
        for (int nt = 0; nt < 2; nt++) {
            int n = n0 + wn + nt * 16 + lane16;
#pragma unroll
            for (int rr = 0; rr < 4; rr++) {
                int m = m0 + wm + mt * 16 + quad * 4 + rr;
                if (m < M) Hout[(size_t)m * FF + n] = f2bf(acc[mt][nt][rr]);
            }
        }
    }
}

// ---------------------------------------------------------------------------
// Row sums over buckets -> dinv. One wave per row, 4 rows/block.
// ---------------------------------------------------------------------------
__global__ __launch_bounds__(256) void rowsum_dinv(const int2* __restrict__ bucket,
                                                   const int* __restrict__ counts,
                                                   float* __restrict__ dinv) {
    int wave = threadIdx.x >> 6, lane = threadIdx.x & 63;
    int r = blockIdx.x * 4 + wave;
    int s = r * CAP;
    int e = s + min(counts[r], CAP);
    float sum = 0.0f;
    for (int i = s + lane; i < e; i += 64) sum += __int_as_float(bucket[i].y);
#pragma unroll
    for (int off = 32; off > 0; off >>= 1) sum += __shfl_xor(sum, off);
    if (lane == 0) dinv[r] = (sum > 0.0f) ? rsqrtf(sum) : 0.0f;
}

// ---------------------------------------------------------------------------
// SpMM inner machinery (shared by spmm_bias_relu and fc_spmm)
// ---------------------------------------------------------------------------
__device__ __forceinline__ void accum8(float* acc, uint4 h, float v) {
    unsigned int d[4] = {h.x, h.y, h.z, h.w};
#pragma unroll
    for (int k = 0; k < 4; k++) {
        float lo = __uint_as_float(d[k] << 16);
        float hi = __uint_as_float(d[k] & 0xFFFF0000u);
        acc[2 * k]     = fmaf(v, lo, acc[2 * k]);
        acc[2 * k + 1] = fmaf(v, hi, acc[2 * k + 1]);
    }
}

__device__ __forceinline__ void spmm_row(const unsigned short* __restrict__ H,
                                         const int* __restrict__ counts,
                                         const int2* __restrict__ bucket,
                                         const float* __restrict__ dinv,
                                         const float* __restrict__ bias,
                                         unsigned short* __restrict__ featOut,
                                         int r, int lane) {
    int s = r * CAP;
    int e = s + min(counts[r], CAP);
    int f0 = lane * 8;
    const unsigned short* Hf = H + f0;
    float acc[8] = {0, 0, 0, 0, 0, 0, 0, 0};

    int i = s;
    int2 p0, p1, p2, p3;
    bool have = (i + 4 <= e);
    if (have) { p0 = bucket[i]; p1 = bucket[i + 1]; p2 = bucket[i + 2]; p3 = bucket[i + 3]; }
    while (have) {
        uint4 a0 = *(const uint4*)(Hf + (size_t)p0.x * FF);
        uint4 a1 = *(const uint4*)(Hf + (size_t)p1.x * FF);
        uint4 a2 = *(const uint4*)(Hf + (size_t)p2.x * FF);
        uint4 a3 = *(const uint4*)(Hf + (size_t)p3.x * FF);
        float v0 = __int_as_float(p0.y) * dinv[p0.x];
        float v1 = __int_as_float(p1.y) * dinv[p1.x];
        float v2 = __int_as_float(p2.y) * dinv[p2.x];
        float v3 = __int_as_float(p3.y) * dinv[p3.x];
        i += 4;
        have = (i + 4 <= e);
        if (have) { p0 = bucket[i]; p1 = bucket[i + 1]; p2 = bucket[i + 2]; p3 = bucket[i + 3]; }
        accum8(acc, a0, v0);
        accum8(acc, a1, v1);
        accum8(acc, a2, v2);
        accum8(acc, a3, v3);
    }
    for (; i < e; i++) {
        int2 p = bucket[i];
        uint4 a = *(const uint4*)(Hf + (size_t)p.x * FF);
        accum8(acc, a, __int_as_float(p.y) * dinv[p.x]);
    }

    float dr = dinv[r];
    float4 b0 = *(const float4*)(bias + f0);
    float4 b1 = *(const float4*)(bias + f0 + 4);
    float bb[8] = {b0.x, b0.y, b0.z, b0.w, b1.x, b1.y, b1.z, b1.w};
    unsigned int o[4];
#pragma unroll
    for (int k = 0; k < 4; k++) {
        float v0 = fmaxf(fmaf(acc[2 * k], dr, bb[2 * k]), 0.0f);
        float v1 = fmaxf(fmaf(acc[2 * k + 1], dr, bb[2 * k + 1]), 0.0f);
        o[k] = (unsigned int)f2bf(v0) | ((unsigned int)f2bf(v1) << 16);
    }
    uint4 ov; ov.x = o[0]; ov.y = o[1]; ov.z = o[2]; ov.w = o[3];
    *(uint4*)(featOut + (size_t)r * FF + f0) = ov;
}

// ---------------------------------------------------------------------------
// Plain SpMM dispatch: one wave per row, 4 rows/block.
// ---------------------------------------------------------------------------
__global__ __launch_bounds__(256) void spmm_bias_relu(const unsigned short* __restrict__ H,
                                                      const int* __restrict__ counts,
                                                      const int2* __restrict__ bucket,
                                                      const float* __restrict__ dinv,
                                                      const float* __restrict__ bias,
                                                      unsigned short* __restrict__ featOut) {
    int wave = threadIdx.x >> 6, lane = threadIdx.x & 63;
    int r = blockIdx.x * 4 + wave;
    spmm_row(H, counts, bucket, dinv, bias, featOut, r, lane);
}

// ---------------------------------------------------------------------------
// MFMA GEMM over transposed weights Bt[n][k]. 64x64 tile, BK=64,
// 4 waves (2x2 of 32x32), XOR-swizzled LDS.
// MODE 0: H store (bf16). MODE 1: out += leaky_relu(v + fbias[n], 0.01)
// ---------------------------------------------------------------------------
template <int MODE>
__global__ __launch_bounds__(256) void gemm_bf16(const unsigned short* __restrict__ A,
                                                 const unsigned short* __restrict__ Bt,
                                                 const float* __restrict__ fbias,
                                                 unsigned short* __restrict__ Hout,
                                                 float* __restrict__ out,
                                                 int M) {
    __shared__ short As[64 * 64];
    __shared__ short Bs[64 * 64];
    int tid = threadIdx.x;
    int wave = tid >> 6;
    int lane = tid & 63;
    int lane16 = lane & 15;
    int quad = lane >> 4;
    int m0 = blockIdx.x * 64;
    int n0 = blockIdx.y * 64;
    int wm = (wave >> 1) * 32;
    int wn = (wave & 1) * 32;

    f32x4 acc[2][2] = {};

    for (int k0 = 0; k0 < FF; k0 += 64) {
#pragma unroll
        for (int s = 0; s < 2; s++) {
            int c = wave * 128 + s * 64 + lane;
            int row = c >> 3;
            int kc = (c & 7) ^ (row & 7);
            int ar = m0 + row; if (ar >= M) ar = M - 1;
            gload16((const short*)A + (size_t)ar * FF + k0 + kc * 8,
                    &As[(wave * 128 + s * 64) * 8]);
            gload16((const short*)Bt + (size_t)(n0 + row) * FF + k0 + kc * 8,
                    &Bs[(wave * 128 + s * 64) * 8]);
        }
        __syncthreads();
#pragma unroll
        for (int kk = 0; kk < 2; kk++) {
            bf16x8 a[2], bb[2];
#pragma unroll
            for (int mt = 0; mt < 2; mt++) {
                int row = wm + mt * 16 + lane16;
                int kc = (kk * 4 + quad) ^ (row & 7);
                a[mt] = *(const bf16x8*)&As[row * 64 + kc * 8];
            }
#pragma unroll
            for (int nt = 0; nt < 2; nt++) {
                int row = wn + nt * 16 + lane16;
                int kc = (kk * 4 + quad) ^ (row & 7);
                bb[nt] = *(const bf16x8*)&Bs[row * 64 + kc * 8];
            }
#pragma unroll
            for (int mt = 0; mt < 2; mt++)
#pragma unroll
                for (int nt = 0; nt < 2; nt++)
                    acc[mt][nt] = __builtin_amdgcn_mfma_f32_16x16x32_bf16(a[mt], bb[nt], acc[mt][nt], 0, 0, 0);
        }
        __syncthreads();
    }

#pragma unroll
    for (int mt = 0; mt < 2; mt++) {
#pragma unroll
        for (int nt = 0; nt < 2; nt++) {
            int n = n0 + wn + nt * 16 + lane16;
            float bv = (MODE == 1) ? fbias[n] : 0.0f;
#pragma unroll
            for (int rr = 0; rr < 4; rr++) {
                int m = m0 + wm + mt * 16 + quad * 4 + rr;
                if (m < M) {
                    float v = acc[mt][nt][rr];
                    if (MODE == 1) {
                        v += bv;
                        v = (v > 0.0f) ? v : 0.01f * v;
                        out[(size_t)m * FF + n] += v;
                    } else {
                        Hout[(size_t)m * FF + n] = f2bf(v);
                    }
                }
            }
        }
    }
}

// ---------------------------------------------------------------------------
// Merged dispatch: fc0 GEMM blocks [0, ngemm) + spmm2 blocks [ngemm, ...).
// fc0: out += leaky(featA @ fW0 + fb0)   (reads featA = feat1)
// spmm2: featB = relu(SpMM(H1) + gb1)     (reads H1, writes featB)
// Independent (both need only feat1/H1); fc0's MFMA hides under the
// latency-bound spmm gathers.
// ---------------------------------------------------------------------------
__global__ __launch_bounds__(256) void fc_spmm(const unsigned short* __restrict__ A,
                                               const unsigned short* __restrict__ Bt,
                                               const float* __restrict__ fbias,
                                               float* __restrict__ out,
                                               int M, int gxm, int ngemm,
                                               const unsigned short* __restrict__ H,
                                               const int* __restrict__ counts,
                                               const int2* __restrict__ bucket,
                                               const float* __restrict__ dinv,
                                               const float* __restrict__ bias,
                                               unsigned short* __restrict__ featOut) {
    __shared__ short As[64 * 64];
    __shared__ short Bs[64 * 64];
    int b = blockIdx.x;
    int tid = threadIdx.x;
    int wave = tid >> 6;
    int lane = tid & 63;
    if (b >= ngemm) {
        // ----- spmm2 -----
        int r = (b - ngemm) * 4 + wave;
        spmm_row(H, counts, bucket, dinv, bias, featOut, r, lane);
        return;
    }
    // ----- fc0 GEMM -----
    int lane16 = lane & 15;
    int quad = lane >> 4;
    int m0 = (b % gxm) * 64;
    int n0 = (b / gxm) * 64;
    int wm = (wave >> 1) * 32;
    int wn = (wave & 1) * 32;

    f32x4 acc[2][2] = {};

    for (int k0 = 0; k0 < FF; k0 += 64) {
#pragma unroll
        for (int s = 0; s < 2; s++) {
            int c = wave * 128 + s * 64 + lane;
            int row = c >> 3;
            int kc = (c & 7) ^ (row & 7);
            int ar = m0 + row; if (ar >= M) ar = M - 1;
            gload16((const short*)A + (size_t)ar * FF + k0 + kc * 8,
                    &As[(wave * 128 + s * 64) * 8]);
            gload16((const short*)Bt + (size_t)(n0 + row) * FF + k0 + kc * 8,
                    &Bs[(wave * 128 + s * 64) * 8]);
        }
        __syncthreads();
#pragma unroll
        for (int kk = 0; kk < 2; kk++) {
            bf16x8 a[2], bb[2];
#pragma unroll
            for (int mt = 0; mt < 2; mt++) {
                int row = wm + mt * 16 + lane16;
                int kc = (kk * 4 + quad) ^ (row & 7);
                a[mt] = *(const bf16x8*)&As[row * 64 + kc * 8];
            }
#pragma unroll
            for (int nt = 0; nt < 2; nt++) {
                int row = wn + nt * 16 + lane16;
                int kc = (kk * 4 + quad) ^ (row & 7);
                bb[nt] = *(const bf16x8*)&Bs[row * 64 + kc * 8];
            }
#pragma unroll
            for (int mt = 0; mt < 2; mt++)
#pragma unroll
                for (int nt = 0; nt < 2; nt++)
                    acc[mt][nt] = __builtin_amdgcn_mfma_f32_16x16x32_bf16(a[mt], bb[nt], acc[mt][nt], 0, 0, 0);
        }
        __syncthreads();
    }

#pragma unroll
    for (int mt = 0; mt < 2; mt++) {
#pragma unroll
        for (int nt = 0; nt < 2; nt++) {
            int n = n0 + wn + nt * 16 + lane16;
            float bv = fbias[n];
#pragma unroll
            for (int rr = 0; rr < 4; rr++) {
                int m = m0 + wm + mt * 16 + quad * 4 + rr;
                if (m < M) {
                    float v = acc[mt][nt][rr] + bv;
                    v = (v > 0.0f) ? v : 0.01f * v;
                    out[(size_t)m * FF + n] += v;
                }
            }
        }
    }
}

// ---------------------------------------------------------------------------
extern "C" void kernel_launch(void* const* d_in, const int* in_sizes, int n_in,
                              void* d_out, int out_size, void* d_ws, size_t ws_size,
                              hipStream_t stream) {
    const float* xa      = (const float*)d_in[0];
    const float* xv      = (const float*)d_in[1];
    const float* xt      = (const float*)d_in[2];
    const float* ew      = (const float*)d_in[3];
    const float* gcn_W   = (const float*)d_in[4];
    const float* gcn_b   = (const float*)d_in[5];
    const float* fc_W    = (const float*)d_in[6];
    const float* fc_b    = (const float*)d_in[7];
    const int*   eidx    = (const int*)d_in[8];
    const int E = in_sizes[8] / 2;
    const int* esrc = eidx;
    const int* edst = eidx + E;

    float* out = (float*)d_out;

    // workspace layout (64B aligned blocks)
    char* w = (char*)d_ws;
    int*   counts  = (int*)  (w + 0);            // 24000 B (pad 24064)
    float* dinv    = (float*)(w + 24064);        // 24000 B (pad to 48128)
    int2*  bucket  = (int2*) (w + 48128);        // 6000*CAP*8 = 6,144,000 B
    unsigned short* featA = (unsigned short*)(w + 6192128);   // 6,144,000 B
    unsigned short* featB = (unsigned short*)(w + 12336128);  // 6,144,000 B
    unsigned short* H     = (unsigned short*)(w + 18480128);  // 6,144,000 B
    unsigned short* Wt    = (unsigned short*)(w + 24624128);  // 2,097,152 B
    int*   pir     = (int*)  (w + 26721280);     // E*4 = 1.6 MB

    hipMemsetAsync(counts, 0, 24000, stream);

    const int eblocks = (E + 255) / 256;
    prep<<<3256 + eblocks, 256, 0, stream>>>(xa, xv, xt, featA, out,
                                             gcn_W, fc_W, Wt, esrc, counts, pir, E);

    const int gxm = (NN + 63) / 64;   // 94
    const int ngemm = gxm * 8;        // 752
    // Wt slots: 0=gW0^T, 1=fW0^T, 2=gW1^T, 3=fW1^T
    // merged: scatter (first) || H0 = featA @ gW0
    gemm0_scatter<<<eblocks + ngemm, 256, 0, stream>>>(featA, Wt, H, NN, gxm, eblocks,
                                                       esrc, edst, ew, pir, bucket, E);
    rowsum_dinv<<<NN / 4, 256, 0, stream>>>(bucket, counts, dinv);

    // feat1 = relu(gcn@H0 + gb0) -> featA (in place over feat0; gemm0 done)
    spmm_bias_relu<<<NN / 4, 256, 0, stream>>>(H, counts, bucket, dinv, gcn_b, featA);
    // H1 = feat1 @ gW1
    gemm_bf16<0><<<dim3(gxm, 8), 256, 0, stream>>>(featA, Wt + (size_t)2 * FF * FF,
                                                   nullptr, H, nullptr, NN);
    // merged: out += leaky(feat1@fW0 + fb0)  ||  featB = relu(gcn@H1 + gb1)
    fc_spmm<<<ngemm + NN / 4, 256, 0, stream>>>(featA, Wt + (size_t)FF * FF, fc_b,
                                                out, NN, gxm, ngemm,
                                                H, counts, bucket, dinv, gcn_b + FF, featB);
    // out += leaky(feat2@fW1 + fb1)
    gemm_bf16<1><<<dim3(gxm, 8), 256, 0, stream>>>(featB, Wt + (size_t)3 * FF * FF,
                                                   fc_b + FF, nullptr, out, NN);
}

// Round 11
// 210.536 us; speedup vs baseline: 1.0933x; 1.0406x over previous
//
#include <hip/hip_runtime.h>
#include <hip/hip_bf16.h>

// Problem constants (from reference)
#define LL 2000
#define MM 3
#define FF 512
#define NN (MM * LL)          // 6000 nodes
#define NUM_LAYERS 2
#define CAP 128               // bucket capacity; deg ~ N(66.7, 8.2) -> P(any>128) ~ 1e-9

typedef __attribute__((ext_vector_type(8))) short bf16x8;
typedef __attribute__((ext_vector_type(4))) float f32x4;

__device__ __forceinline__ unsigned short f2bf(float x) {
    __hip_bfloat16 b = __float2bfloat16(x);
    return *(unsigned short*)&b;
}

// async global->LDS, 16B per lane. lds dest is wave-uniform base + lane*16.
__device__ __forceinline__ void gload16(const void* gsrc, void* ldst) {
    __builtin_amdgcn_global_load_lds((const __attribute__((address_space(1))) unsigned int*)gsrc,
                                     (__attribute__((address_space(3))) unsigned int*)ldst,
                                     16, 0, 0);
}

// ---------------------------------------------------------------------------
// Fused prep: block-range dispatch.
//  [0, 3000):     concat [x_a;x_v;x_t] -> feat bf16, out fp32 init
//  [3000, 3256):  weight transpose+cvt, slots: 0=gW0^T 1=fW0^T 2=gW1^T 3=fW1^T
//  [3256, ...):   edge histogram: pir[e] = rank of edge e within its row
//                 (single atomic/edge; hides under the streaming concat)
// ---------------------------------------------------------------------------
__global__ __launch_bounds__(256) void prep(const float* __restrict__ xa,
                                            const float* __restrict__ xv,
                                            const float* __restrict__ xt,
                                            unsigned short* __restrict__ feat,
                                            float* __restrict__ out_sum,
                                            const float* __restrict__ gcnW,
                                            const float* __restrict__ fcW,
                                            unsigned short* __restrict__ Wt,
                                            const int* __restrict__ esrc,
                                            int* __restrict__ counts,
                                            int* __restrict__ pir, int E) {
    __shared__ unsigned short tile[64][65];
    int b = blockIdx.x;
    int tid = threadIdx.x;
    if (b < 3000) {
        // ----- concat -----
        int idx4 = b * 256 + tid;
        const int per4 = (LL * FF) / 4;
        const float4* src;
        int off;
        if (idx4 < per4)            { src = (const float4*)xa; off = idx4; }
        else if (idx4 < 2 * per4)   { src = (const float4*)xv; off = idx4 - per4; }
        else                        { src = (const float4*)xt; off = idx4 - 2 * per4; }
        float4 v = src[off];
        ((float4*)out_sum)[idx4] = v;
        ushort4 pk;
        pk.x = f2bf(v.x); pk.y = f2bf(v.y); pk.z = f2bf(v.z); pk.w = f2bf(v.w);
        ((ushort4*)feat)[idx4] = pk;
    } else if (b < 3256) {
        // ----- wtrans -----
        int idx = b - 3000;
        int mz = idx >> 6;          // 0,1 gcn ; 2,3 fc
        int rem = idx & 63;
        int k0 = (rem >> 3) * 64;
        int n0 = (rem & 7) * 64;
        int layer = (mz < 2) ? mz : mz - 2;
        const float* src = (mz < 2) ? (gcnW + (size_t)layer * FF * FF)
                                    : (fcW + (size_t)layer * FF * FF);
        int slot = (mz < 2) ? (mz * 2) : ((mz - 2) * 2 + 1);
        unsigned short* dst = Wt + (size_t)slot * FF * FF;
        for (int i = tid; i < 64 * 64; i += 256) {
            int r = i >> 6, c = i & 63;
            tile[r][c] = f2bf(src[(size_t)(k0 + r) * FF + n0 + c]);
        }
        __syncthreads();
        for (int i = tid; i < 64 * 64; i += 256) {
            int r = i >> 6, c = i & 63;
            dst[(size_t)(n0 + r) * FF + k0 + c] = tile[c][r];
        }
    } else {
        // ----- edge histogram -----
        int e = (b - 3256) * 256 + tid;
        if (e < E) pir[e] = atomicAdd(&counts[esrc[e]], 1);
    }
}

// ---------------------------------------------------------------------------
// Merged dispatch: scatter blocks [0, sblk) + gemm0 blocks [sblk, ...).
// Scatter first: long-latency random stores start earliest, hide under MFMA.
// scatter (atomic-free): bucket[r*CAP + pir[e]] = {col, bits(w)}
// gemm0: H = feat @ gW0 (64x64 tile, store bf16).
// ---------------------------------------------------------------------------
__global__ __launch_bounds__(256) void gemm0_scatter(const unsigned short* __restrict__ A,
                                                     const unsigned short* __restrict__ Bt,
                                                     unsigned short* __restrict__ Hout,
                                                     int M, int gxm, int sblk,
                                                     const int* __restrict__ esrc,
                                                     const int* __restrict__ edst,
                                                     const float* __restrict__ ew,
                                                     const int* __restrict__ pir,
                                                     int2* __restrict__ bucket, int E) {
    __shared__ short As[64 * 64];
    __shared__ short Bs[64 * 64];
    int b = blockIdx.x;
    int tid = threadIdx.x;
    if (b < sblk) {
        // ----- scatter -----
        int e = b * 256 + tid;
        if (e < E) {
            int r = esrc[e];
            int slot = pir[e];
            if (slot < CAP) {
                int2 p;
                p.x = edst[e];
                p.y = __float_as_int(ew[e]);
                bucket[(size_t)r * CAP + slot] = p;
            }
        }
        return;
    }
    // ----- gemm0 -----
    int bg = b - sblk;
    int wave = tid >> 6;
    int lane = tid & 63;
    int lane16 = lane & 15;
    int quad = lane >> 4;
    int m0 = (bg % gxm) * 64;
    int n0 = (bg / gxm) * 64;
    int wm = (wave >> 1) * 32;
    int wn = (wave & 1) * 32;

    f32x4 acc[2][2] = {};

    for (int k0 = 0; k0 < FF; k0 += 64) {
#pragma unroll
        for (int s = 0; s < 2; s++) {
            int c = wave * 128 + s * 64 + lane;
            int row = c >> 3;
            int kc = (c & 7) ^ (row & 7);
            int ar = m0 + row; if (ar >= M) ar = M - 1;
            gload16((const short*)A + (size_t)ar * FF + k0 + kc * 8,
                    &As[(wave * 128 + s * 64) * 8]);
            gload16((const short*)Bt + (size_t)(n0 + row) * FF + k0 + kc * 8,
                    &Bs[(wave * 128 + s * 64) * 8]);
        }
        __syncthreads();
#pragma unroll
        for (int kk = 0; kk < 2; kk++) {
            bf16x8 a[2], bb[2];
#pragma unroll
            for (int mt = 0; mt < 2; mt++) {
                int row = wm + mt * 16 + lane16;
                int kc = (kk * 4 + quad) ^ (row & 7);
                a[mt] = *(const bf16x8*)&As[row * 64 + kc * 8];
            }
#pragma unroll
            for (int nt = 0; nt < 2; nt++) {
                int row = wn + nt * 16 + lane16;
                int kc = (kk * 4 + quad) ^ (row & 7);
                bb[nt] = *(const bf16x8*)&Bs[row * 64 + kc * 8];
            }
#pragma unroll
            for (int mt = 0; mt < 2; mt++)
#pragma unroll
                for (int nt = 0; nt < 2; nt++)
                    acc[mt][nt] = __builtin_amdgcn_mfma_f32_16x16x32_bf16(a[mt], bb[nt], acc[mt][nt], 0, 0, 0);
        }
        __syncthreads();
    }

#pragma unroll
    for (int mt = 0; mt < 2; mt++) {
#pragma unroll
        for (int nt = 0; nt < 2; nt++) {
            int n = n0 + wn + nt * 16 + lane16;
#pragma unroll
            for (int rr = 0; rr < 4; rr++) {
                int m = m0 + wm + mt * 16 + quad * 4 + rr;
                if (m < M) Hout[(size_t)m * FF + n] = f2bf(acc[mt][nt][rr]);
            }
        }
    }
}

// ---------------------------------------------------------------------------
// Row sums over buckets -> dinv. One wave per row, 4 rows/block.
// ---------------------------------------------------------------------------
__global__ __launch_bounds__(256) void rowsum_dinv(const int2* __restrict__ bucket,
                                                   const int* __restrict__ counts,
                                                   float* __restrict__ dinv) {
    int wave = threadIdx.x >> 6, lane = threadIdx.x & 63;
    int r = blockIdx.x * 4 + wave;
    int s = r * CAP;
    int e = s + min(counts[r], CAP);
    float sum = 0.0f;
    for (int i = s + lane; i < e; i += 64) sum += __int_as_float(bucket[i].y);
#pragma unroll
    for (int off = 32; off > 0; off >>= 1) sum += __shfl_xor(sum, off);
    if (lane == 0) dinv[r] = (sum > 0.0f) ? rsqrtf(sum) : 0.0f;
}

// ---------------------------------------------------------------------------
// SpMM gather over buckets, feature-half split for per-XCD L2 residency:
//   feat[r, half] = relu( dinv[r] * sum_e (w_e*dinv[c_e]) * H[c_e, half] + b )
// Each block: one 256-feature half (H-half = 3 MB < 4 MB XCD L2) x 8 rows.
// half = blockIdx&1 -> partitions XCDs by parity under round-robin dispatch.
// Wave = 2 rows x 32 lanes x 8 feats (16B dwordx4). Unroll-4 pipelined.
// ---------------------------------------------------------------------------
__device__ __forceinline__ void accum8(float* acc, uint4 h, float v) {
    unsigned int d[4] = {h.x, h.y, h.z, h.w};
#pragma unroll
    for (int k = 0; k < 4; k++) {
        float lo = __uint_as_float(d[k] << 16);
        float hi = __uint_as_float(d[k] & 0xFFFF0000u);
        acc[2 * k]     = fmaf(v, lo, acc[2 * k]);
        acc[2 * k + 1] = fmaf(v, hi, acc[2 * k + 1]);
    }
}

__global__ __launch_bounds__(256) void spmm_bias_relu(const unsigned short* __restrict__ H,
                                                      const int* __restrict__ counts,
                                                      const int2* __restrict__ bucket,
                                                      const float* __restrict__ dinv,
                                                      const float* __restrict__ bias,
                                                      unsigned short* __restrict__ featOut) {
    int wave = threadIdx.x >> 6, lane = threadIdx.x & 63;
    int half = blockIdx.x & 1;
    int rowbase = (blockIdx.x >> 1) * 8;
    int sub = lane >> 5;           // row within wave
    int l = lane & 31;
    int r = rowbase + wave * 2 + sub;
    int f0 = half * 256 + l * 8;
    const unsigned short* Hf = H + f0;
    int s = r * CAP;
    int e = s + min(counts[r], CAP);
    float acc[8] = {0, 0, 0, 0, 0, 0, 0, 0};

    int i = s;
    int2 p0, p1, p2, p3;
    bool have = (i + 4 <= e);
    if (have) { p0 = bucket[i]; p1 = bucket[i + 1]; p2 = bucket[i + 2]; p3 = bucket[i + 3]; }
    while (have) {
        uint4 a0 = *(const uint4*)(Hf + (size_t)p0.x * FF);
        uint4 a1 = *(const uint4*)(Hf + (size_t)p1.x * FF);
        uint4 a2 = *(const uint4*)(Hf + (size_t)p2.x * FF);
        uint4 a3 = *(const uint4*)(Hf + (size_t)p3.x * FF);
        float v0 = __int_as_float(p0.y) * dinv[p0.x];
        float v1 = __int_as_float(p1.y) * dinv[p1.x];
        float v2 = __int_as_float(p2.y) * dinv[p2.x];
        float v3 = __int_as_float(p3.y) * dinv[p3.x];
        i += 4;
        have = (i + 4 <= e);
        if (have) { p0 = bucket[i]; p1 = bucket[i + 1]; p2 = bucket[i + 2]; p3 = bucket[i + 3]; }
        accum8(acc, a0, v0);
        accum8(acc, a1, v1);
        accum8(acc, a2, v2);
        accum8(acc, a3, v3);
    }
    for (; i < e; i++) {
        int2 p = bucket[i];
        uint4 a = *(const uint4*)(Hf + (size_t)p.x * FF);
        accum8(acc, a, __int_as_float(p.y) * dinv[p.x]);
    }

    float dr = dinv[r];
    float4 b0 = *(const float4*)(bias + f0);
    float4 b1 = *(const float4*)(bias + f0 + 4);
    float bb[8] = {b0.x, b0.y, b0.z, b0.w, b1.x, b1.y, b1.z, b1.w};
    unsigned int o[4];
#pragma unroll
    for (int k = 0; k < 4; k++) {
        float v0 = fmaxf(fmaf(acc[2 * k], dr, bb[2 * k]), 0.0f);
        float v1 = fmaxf(fmaf(acc[2 * k + 1], dr, bb[2 * k + 1]), 0.0f);
        o[k] = (unsigned int)f2bf(v0) | ((unsigned int)f2bf(v1) << 16);
    }
    uint4 ov; ov.x = o[0]; ov.y = o[1]; ov.z = o[2]; ov.w = o[3];
    *(uint4*)(featOut + (size_t)r * FF + f0) = ov;
}

// ---------------------------------------------------------------------------
// MFMA GEMM over stacked transposed weights Bt[n][k]. 64x64 tile, BK=64,
// 256 threads = 4 waves (2x2 of 32x32), XOR-swizzled LDS.
// MODE 1: all cols -> out += leaky_relu(v + fbias[n]), grid.y = 8
// MODE 2: n0<512 -> out += leaky_relu(v + fbias[n]); n0>=512 -> H store at
//         n-512, grid.y = 16 (Bt = [fW_i^T ; gW_{i+1}^T], same input feat)
// ---------------------------------------------------------------------------
template <int MODE>
__global__ __launch_bounds__(256) void gemm_bf16(const unsigned short* __restrict__ A,
                                                 const unsigned short* __restrict__ Bt,
                                                 const float* __restrict__ fbias,
                                                 unsigned short* __restrict__ Hout,
                                                 float* __restrict__ out,
                                                 int M) {
    __shared__ short As[64 * 64];
    __shared__ short Bs[64 * 64];
    int tid = threadIdx.x;
    int wave = tid >> 6;
    int lane = tid & 63;
    int lane16 = lane & 15;
    int quad = lane >> 4;
    int m0 = blockIdx.x * 64;
    int n0 = blockIdx.y * 64;
    int wm = (wave >> 1) * 32;
    int wn = (wave & 1) * 32;

    f32x4 acc[2][2] = {};

    for (int k0 = 0; k0 < FF; k0 += 64) {
#pragma unroll
        for (int s = 0; s < 2; s++) {
            int c = wave * 128 + s * 64 + lane;
            int row = c >> 3;
            int kc = (c & 7) ^ (row & 7);
            int ar = m0 + row; if (ar >= M) ar = M - 1;
            gload16((const short*)A + (size_t)ar * FF + k0 + kc * 8,
                    &As[(wave * 128 + s * 64) * 8]);
            gload16((const short*)Bt + (size_t)(n0 + row) * FF + k0 + kc * 8,
                    &Bs[(wave * 128 + s * 64) * 8]);
        }
        __syncthreads();
#pragma unroll
        for (int kk = 0; kk < 2; kk++) {
            bf16x8 a[2], bb[2];
#pragma unroll
            for (int mt = 0; mt < 2; mt++) {
                int row = wm + mt * 16 + lane16;
                int kc = (kk * 4 + quad) ^ (row & 7);
                a[mt] = *(const bf16x8*)&As[row * 64 + kc * 8];
            }
#pragma unroll
            for (int nt = 0; nt < 2; nt++) {
                int row = wn + nt * 16 + lane16;
                int kc = (kk * 4 + quad) ^ (row & 7);
                bb[nt] = *(const bf16x8*)&Bs[row * 64 + kc * 8];
            }
#pragma unroll
            for (int mt = 0; mt < 2; mt++)
#pragma unroll
                for (int nt = 0; nt < 2; nt++)
                    acc[mt][nt] = __builtin_amdgcn_mfma_f32_16x16x32_bf16(a[mt], bb[nt], acc[mt][nt], 0, 0, 0);
        }
        __syncthreads();
    }

    bool isFc = (MODE == 1) || (MODE == 2 && n0 < FF);
#pragma unroll
    for (int mt = 0; mt < 2; mt++) {
#pragma unroll
        for (int nt = 0; nt < 2; nt++) {
            int n = n0 + wn + nt * 16 + lane16;
            float bv = isFc ? fbias[n] : 0.0f;
#pragma unroll
            for (int rr = 0; rr < 4; rr++) {
                int m = m0 + wm + mt * 16 + quad * 4 + rr;
                if (m < M) {
                    float v = acc[mt][nt][rr];
                    if (isFc) {
                        v += bv;
                        v = (v > 0.0f) ? v : 0.01f * v;
                        out[(size_t)m * FF + n] += v;
                    } else {
                        Hout[(size_t)m * FF + (n - FF)] = f2bf(v);
                    }
                }
            }
        }
    }
}

// ---------------------------------------------------------------------------
extern "C" void kernel_launch(void* const* d_in, const int* in_sizes, int n_in,
                              void* d_out, int out_size, void* d_ws, size_t ws_size,
                              hipStream_t stream) {
    const float* xa      = (const float*)d_in[0];
    const float* xv      = (const float*)d_in[1];
    const float* xt      = (const float*)d_in[2];
    const float* ew      = (const float*)d_in[3];
    const float* gcn_W   = (const float*)d_in[4];
    const float* gcn_b   = (const float*)d_in[5];
    const float* fc_W    = (const float*)d_in[6];
    const float* fc_b    = (const float*)d_in[7];
    const int*   eidx    = (const int*)d_in[8];
    const int E = in_sizes[8] / 2;
    const int* esrc = eidx;
    const int* edst = eidx + E;

    float* out = (float*)d_out;

    // workspace layout (64B aligned blocks)
    char* w = (char*)d_ws;
    int*   counts  = (int*)  (w + 0);            // 24000 B (pad 24064)
    float* dinv    = (float*)(w + 24064);        // 24000 B (pad to 48128)
    int2*  bucket  = (int2*) (w + 48128);        // 6000*CAP*8 = 6,144,000 B
    unsigned short* feat = (unsigned short*)(w + 6192128);    // 6,144,000 B
    unsigned short* H    = (unsigned short*)(w + 12336128);   // 6,144,000 B
    unsigned short* Wt   = (unsigned short*)(w + 18480128);   // 2,097,152 B
    int*   pir     = (int*)  (w + 20577280);     // E*4 = 1.6 MB (own region:
                                                 // scatter runs concurrently with gemm0->H)

    hipMemsetAsync(counts, 0, 24000, stream);

    const int eblocks = (E + 255) / 256;
    prep<<<3256 + eblocks, 256, 0, stream>>>(xa, xv, xt, feat, out,
                                             gcn_W, fc_W, Wt, esrc, counts, pir, E);

    const int gxm = (NN + 63) / 64;   // 94
    const int ngemm0 = gxm * 8;       // 752
    // Wt slots: 0=gW0^T, 1=fW0^T, 2=gW1^T, 3=fW1^T (slots 1,2 contiguous)
    // merged: scatter (first, starts early) || H0 = feat0 @ gW0
    gemm0_scatter<<<eblocks + ngemm0, 256, 0, stream>>>(feat, Wt, H, NN, gxm, eblocks,
                                                        esrc, edst, ew, pir, bucket, E);
    rowsum_dinv<<<NN / 4, 256, 0, stream>>>(bucket, counts, dinv);

    // feat1 = relu(gcn@H0 + gb0)   (feature-half split, 1500 blocks)
    spmm_bias_relu<<<(NN / 8) * 2, 256, 0, stream>>>(H, counts, bucket, dinv, gcn_b, feat);
    // out += leaky(feat1@fW0 + fb0)  AND  H1 = feat1 @ gW1   (fused)
    gemm_bf16<2><<<dim3(gxm, 16), 256, 0, stream>>>(feat, Wt + (size_t)FF * FF, fc_b, H, out, NN);
    // feat2 = relu(gcn@H1 + gb1)
    spmm_bias_relu<<<(NN / 8) * 2, 256, 0, stream>>>(H, counts, bucket, dinv, gcn_b + FF, feat);
    // out += leaky(feat2@fW1 + fb1)
    gemm_bf16<1><<<dim3(gxm, 8), 256, 0, stream>>>(feat, Wt + (size_t)3 * FF * FF, fc_b + FF, nullptr, out, NN);
}

// Round 13
// 206.559 us; speedup vs baseline: 1.1143x; 1.0193x over previous
//
#include <hip/hip_runtime.h>
#include <hip/hip_bf16.h>

// Problem constants (from reference)
#define LL 2000
#define MM 3
#define FF 512
#define NN (MM * LL)          // 6000 nodes
#define CAP 128               // bucket capacity; deg ~ N(66.7, 8.2) -> P(any>128) ~ 1e-9

typedef __attribute__((ext_vector_type(8))) short bf16x8;
typedef __attribute__((ext_vector_type(4))) float f32x4;

__device__ __forceinline__ unsigned short f2bf(float x) {
    __hip_bfloat16 b = __float2bfloat16(x);
    return *(unsigned short*)&b;
}

// async global->LDS, 16B per lane. lds dest is wave-uniform base + lane*16.
__device__ __forceinline__ void gload16(const void* gsrc, void* ldst) {
    __builtin_amdgcn_global_load_lds((const __attribute__((address_space(1))) unsigned int*)gsrc,
                                     (__attribute__((address_space(3))) unsigned int*)ldst,
                                     16, 0, 0);
}

// ---------------------------------------------------------------------------
// Fused prep: block-range dispatch.
//  [0, 3000):     concat [x_a;x_v;x_t] -> feat bf16, out fp32 init
//  [3000, 3256):  weight transpose+cvt, slots: 0=gW0^T 1=fW0^T 2=gW1^T 3=fW1^T
//  [3256, ...):   edge histogram: pir[e] = rank of edge e within its row
// ---------------------------------------------------------------------------
__global__ __launch_bounds__(256) void prep(const float* __restrict__ xa,
                                            const float* __restrict__ xv,
                                            const float* __restrict__ xt,
                                            unsigned short* __restrict__ feat,
                                            float* __restrict__ out_sum,
                                            const float* __restrict__ gcnW,
                                            const float* __restrict__ fcW,
                                            unsigned short* __restrict__ Wt,
                                            const int* __restrict__ esrc,
                                            int* __restrict__ counts,
                                            int* __restrict__ pir, int E) {
    __shared__ unsigned short tile[64][65];
    int b = blockIdx.x;
    int tid = threadIdx.x;
    if (b < 3000) {
        // ----- concat -----
        int idx4 = b * 256 + tid;
        const int per4 = (LL * FF) / 4;
        const float4* src;
        int off;
        if (idx4 < per4)            { src = (const float4*)xa; off = idx4; }
        else if (idx4 < 2 * per4)   { src = (const float4*)xv; off = idx4 - per4; }
        else                        { src = (const float4*)xt; off = idx4 - 2 * per4; }
        float4 v = src[off];
        ((float4*)out_sum)[idx4] = v;
        ushort4 pk;
        pk.x = f2bf(v.x); pk.y = f2bf(v.y); pk.z = f2bf(v.z); pk.w = f2bf(v.w);
        ((ushort4*)feat)[idx4] = pk;
    } else if (b < 3256) {
        // ----- wtrans -----
        int idx = b - 3000;
        int mz = idx >> 6;          // 0,1 gcn ; 2,3 fc
        int rem = idx & 63;
        int k0 = (rem >> 3) * 64;
        int n0 = (rem & 7) * 64;
        int layer = (mz < 2) ? mz : mz - 2;
        const float* src = (mz < 2) ? (gcnW + (size_t)layer * FF * FF)
                                    : (fcW + (size_t)layer * FF * FF);
        int slot = (mz < 2) ? (mz * 2) : ((mz - 2) * 2 + 1);
        unsigned short* dst = Wt + (size_t)slot * FF * FF;
        for (int i = tid; i < 64 * 64; i += 256) {
            int r = i >> 6, c = i & 63;
            tile[r][c] = f2bf(src[(size_t)(k0 + r) * FF + n0 + c]);
        }
        __syncthreads();
        for (int i = tid; i < 64 * 64; i += 256) {
            int r = i >> 6, c = i & 63;
            dst[(size_t)(n0 + r) * FF + k0 + c] = tile[c][r];
        }
    } else {
        // ----- edge histogram -----
        int e = (b - 3256) * 256 + tid;
        if (e < E) pir[e] = atomicAdd(&counts[esrc[e]], 1);
    }
}

// ---------------------------------------------------------------------------
// Merged dispatch: scatter blocks [0, sblk) + gemm0 blocks [sblk, ...).
// Scatter first: long-latency random stores start earliest, hide under MFMA.
// scatter (atomic-free, 4B packed): bucket[r*CAP + pir[e]] = bf16(w)<<16 | col
// gemm0: H = feat @ gW0 (64x64 tile, store bf16).
// ---------------------------------------------------------------------------
__global__ __launch_bounds__(256) void gemm0_scatter(const unsigned short* __restrict__ A,
                                                     const unsigned short* __restrict__ Bt,
                                                     unsigned short* __restrict__ Hout,
                                                     int M, int gxm, int sblk,
                                                     const int* __restrict__ esrc,
                                                     const int* __restrict__ edst,
                                                     const float* __restrict__ ew,
                                                     const int* __restrict__ pir,
                                                     unsigned int* __restrict__ bucket, int E) {
    __shared__ short As[64 * 64];
    __shared__ short Bs[64 * 64];
    int b = blockIdx.x;
    int tid = threadIdx.x;
    if (b < sblk) {
        // ----- scatter -----
        int e = b * 256 + tid;
        if (e < E) {
            int r = esrc[e];
            int slot = pir[e];
            if (slot < CAP)
                bucket[(size_t)r * CAP + slot] =
                    ((unsigned int)f2bf(ew[e]) << 16) | (unsigned int)edst[e];
        }
        return;
    }
    // ----- gemm0 -----
    int bg = b - sblk;
    int wave = tid >> 6;
    int lane = tid & 63;
    int lane16 = lane & 15;
    int quad = lane >> 4;
    int m0 = (bg % gxm) * 64;
    int n0 = (bg / gxm) * 64;
    int wm = (wave >> 1) * 32;
    int wn = (wave & 1) * 32;

    f32x4 acc[2][2] = {};

    for (int k0 = 0; k0 < FF; k0 += 64) {
#pragma unroll
        for (int s = 0; s < 2; s++) {
            int c = wave * 128 + s * 64 + lane;
            int row = c >> 3;
            int kc = (c & 7) ^ (row & 7);
            int ar = m0 + row; if (ar >= M) ar = M - 1;
            gload16((const short*)A + (size_t)ar * FF + k0 + kc * 8,
                    &As[(wave * 128 + s * 64) * 8]);
            gload16((const short*)Bt + (size_t)(n0 + row) * FF + k0 + kc * 8,
                    &Bs[(wave * 128 + s * 64) * 8]);
        }
        __syncthreads();
#pragma unroll
        for (int kk = 0; kk < 2; kk++) {
            bf16x8 a[2], bb[2];
#pragma unroll
            for (int mt = 0; mt < 2; mt++) {
                int row = wm + mt * 16 + lane16;
                int kc = (kk * 4 + quad) ^ (row & 7);
                a[mt] = *(const bf16x8*)&As[row * 64 + kc * 8];
            }
#pragma unroll
            for (int nt = 0; nt < 2; nt++) {
                int row = wn + nt * 16 + lane16;
                int kc = (kk * 4 + quad) ^ (row & 7);
                bb[nt] = *(const bf16x8*)&Bs[row * 64 + kc * 8];
            }
#pragma unroll
            for (int mt = 0; mt < 2; mt++)
#pragma unroll
                for (int nt = 0; nt < 2; nt++)
                    acc[mt][nt] = __builtin_amdgcn_mfma_f32_16x16x32_bf16(a[mt], bb[nt], acc[mt][nt], 0, 0, 0);
        }
        __syncthreads();
    }

#pragma unroll
    for (int mt = 0; mt < 2; mt++) {
#pragma unroll
        for (int nt = 0; nt < 2; nt++) {
            int n = n0 + wn + nt * 16 + lane16;
#pragma unroll
            for (int rr = 0; rr < 4; rr++) {
                int m = m0 + wm + mt * 16 + quad * 4 + rr;
                if (m < M) Hout[(size_t)m * FF + n] = f2bf(acc[mt][nt][rr]);
            }
        }
    }
}

// ---------------------------------------------------------------------------
// Row sums over packed buckets -> dinv. One wave per row, 4 rows/block.
// ---------------------------------------------------------------------------
__global__ __launch_bounds__(256) void rowsum_dinv(const unsigned int* __restrict__ bucket,
                                                   const int* __restrict__ counts,
                                                   float* __restrict__ dinv) {
    int wave = threadIdx.x >> 6, lane = threadIdx.x & 63;
    int r = blockIdx.x * 4 + wave;
    int s = r * CAP;
    int e = s + min(counts[r], CAP);
    float sum = 0.0f;
    for (int i = s + lane; i < e; i += 64)
        sum += __uint_as_float(bucket[i] & 0xFFFF0000u);
#pragma unroll
    for (int off = 32; off > 0; off >>= 1) sum += __shfl_xor(sum, off);
    if (lane == 0) dinv[r] = (sum > 0.0f) ? rsqrtf(sum) : 0.0f;
}

// ---------------------------------------------------------------------------
// SpMM gather over packed buckets:
//   feat[r,:] = relu( dinv[r] * sum_e (w_e*dinv[c_e]) * H[c_e,:] + bias )
// One WAVE per row; lane covers 8 features (16B dwordx4 -> full 1KB H row per
// wave-load). 4 edges prefetched per single uint4 load. dinv[c] wave-uniform
// from a 24KB cache-resident table.
// ---------------------------------------------------------------------------
__device__ __forceinline__ void accum8(float* acc, uint4 h, float v) {
    unsigned int d[4] = {h.x, h.y, h.z, h.w};
#pragma unroll
    for (int k = 0; k < 4; k++) {
        float lo = __uint_as_float(d[k] << 16);
        float hi = __uint_as_float(d[k] & 0xFFFF0000u);
        acc[2 * k]     = fmaf(v, lo, acc[2 * k]);
        acc[2 * k + 1] = fmaf(v, hi, acc[2 * k + 1]);
    }
}

__global__ __launch_bounds__(256) void spmm_bias_relu(const unsigned short* __restrict__ H,
                                                      const int* __restrict__ counts,
                                                      const unsigned int* __restrict__ bucket,
                                                      const float* __restrict__ dinv,
                                                      const float* __restrict__ bias,
                                                      unsigned short* __restrict__ featOut) {
    int wave = threadIdx.x >> 6, lane = threadIdx.x & 63;
    int r = blockIdx.x * 4 + wave;
    int s = r * CAP;
    int e = s + min(counts[r], CAP);
    int f0 = lane * 8;
    const unsigned short* Hf = H + f0;
    float acc[8] = {0, 0, 0, 0, 0, 0, 0, 0};

    int i = s;
    uint4 pk;
    bool have = (i + 4 <= e);
    if (have) pk = *(const uint4*)&bucket[i];
    while (have) {
        unsigned int q0 = pk.x, q1 = pk.y, q2 = pk.z, q3 = pk.w;
        uint4 a0 = *(const uint4*)(Hf + (size_t)(q0 & 0xFFFF) * FF);
        uint4 a1 = *(const uint4*)(Hf + (size_t)(q1 & 0xFFFF) * FF);
        uint4 a2 = *(const uint4*)(Hf + (size_t)(q2 & 0xFFFF) * FF);
        uint4 a3 = *(const uint4*)(Hf + (size_t)(q3 & 0xFFFF) * FF);
        float v0 = __uint_as_float(q0 & 0xFFFF0000u) * dinv[q0 & 0xFFFF];
        float v1 = __uint_as_float(q1 & 0xFFFF0000u) * dinv[q1 & 0xFFFF];
        float v2 = __uint_as_float(q2 & 0xFFFF0000u) * dinv[q2 & 0xFFFF];
        float v3 = __uint_as_float(q3 & 0xFFFF0000u) * dinv[q3 & 0xFFFF];
        i += 4;
        have = (i + 4 <= e);
        if (have) pk = *(const uint4*)&bucket[i];
        accum8(acc, a0, v0);
        accum8(acc, a1, v1);
        accum8(acc, a2, v2);
        accum8(acc, a3, v3);
    }
    for (; i < e; i++) {
        unsigned int q = bucket[i];
        uint4 a = *(const uint4*)(Hf + (size_t)(q & 0xFFFF) * FF);
        accum8(acc, a, __uint_as_float(q & 0xFFFF0000u) * dinv[q & 0xFFFF]);
    }

    float dr = dinv[r];
    float4 b0 = *(const float4*)(bias + f0);
    float4 b1 = *(const float4*)(bias + f0 + 4);
    float bb[8] = {b0.x, b0.y, b0.z, b0.w, b1.x, b1.y, b1.z, b1.w};
    unsigned int o[4];
#pragma unroll
    for (int k = 0; k < 4; k++) {
        float v0 = fmaxf(fmaf(acc[2 * k], dr, bb[2 * k]), 0.0f);
        float v1 = fmaxf(fmaf(acc[2 * k + 1], dr, bb[2 * k + 1]), 0.0f);
        o[k] = (unsigned int)f2bf(v0) | ((unsigned int)f2bf(v1) << 16);
    }
    uint4 ov; ov.x = o[0]; ov.y = o[1]; ov.z = o[2]; ov.w = o[3];
    *(uint4*)(featOut + (size_t)r * FF + f0) = ov;
}

// ---------------------------------------------------------------------------
// MFMA GEMM over stacked transposed weights Bt[n][k]. 64x64 tile, BK=64,
// 256 threads = 4 waves (2x2 of 32x32), XOR-swizzled LDS.
// MODE 1: all cols -> out += leaky_relu(v + fbias[n]), grid.y = 8
// MODE 2: n0<512 -> out += leaky_relu(v + fbias[n]); n0>=512 -> H store at
//         n-512, grid.y = 16 (Bt = [fW_i^T ; gW_{i+1}^T], same input feat)
// ---------------------------------------------------------------------------
template <int MODE>
__global__ __launch_bounds__(256) void gemm_bf16(const unsigned short* __restrict__ A,
                                                 const unsigned short* __restrict__ Bt,
                                                 const float* __restrict__ fbias,
                                                 unsigned short* __restrict__ Hout,
                                                 float* __restrict__ out,
                                                 int M) {
    __shared__ short As[64 * 64];
    __shared__ short Bs[64 * 64];
    int tid = threadIdx.x;
    int wave = tid >> 6;
    int lane = tid & 63;
    int lane16 = lane & 15;
    int quad = lane >> 4;
    int m0 = blockIdx.x * 64;
    int n0 = blockIdx.y * 64;
    int wm = (wave >> 1) * 32;
    int wn = (wave & 1) * 32;

    f32x4 acc[2][2] = {};

    for (int k0 = 0; k0 < FF; k0 += 64) {
#pragma unroll
        for (int s = 0; s < 2; s++) {
            int c = wave * 128 + s * 64 + lane;
            int row = c >> 3;
            int kc = (c & 7) ^ (row & 7);
            int ar = m0 + row; if (ar >= M) ar = M - 1;
            gload16((const short*)A + (size_t)ar * FF + k0 + kc * 8,
                    &As[(wave * 128 + s * 64) * 8]);
            gload16((const short*)Bt + (size_t)(n0 + row) * FF + k0 + kc * 8,
                    &Bs[(wave * 128 + s * 64) * 8]);
        }
        __syncthreads();
#pragma unroll
        for (int kk = 0; kk < 2; kk++) {
            bf16x8 a[2], bb[2];
#pragma unroll
            for (int mt = 0; mt < 2; mt++) {
                int row = wm + mt * 16 + lane16;
                int kc = (kk * 4 + quad) ^ (row & 7);
                a[mt] = *(const bf16x8*)&As[row * 64 + kc * 8];
            }
#pragma unroll
            for (int nt = 0; nt < 2; nt++) {
                int row = wn + nt * 16 + lane16;
                int kc = (kk * 4 + quad) ^ (row & 7);
                bb[nt] = *(const bf16x8*)&Bs[row * 64 + kc * 8];
            }
#pragma unroll
            for (int mt = 0; mt < 2; mt++)
#pragma unroll
                for (int nt = 0; nt < 2; nt++)
                    acc[mt][nt] = __builtin_amdgcn_mfma_f32_16x16x32_bf16(a[mt], bb[nt], acc[mt][nt], 0, 0, 0);
        }
        __syncthreads();
    }

    bool isFc = (MODE == 1) || (MODE == 2 && n0 < FF);
#pragma unroll
    for (int mt = 0; mt < 2; mt++) {
#pragma unroll
        for (int nt = 0; nt < 2; nt++) {
            int n = n0 + wn + nt * 16 + lane16;
            float bv = isFc ? fbias[n] : 0.0f;
#pragma unroll
            for (int rr = 0; rr < 4; rr++) {
                int m = m0 + wm + mt * 16 + quad * 4 + rr;
                if (m < M) {
                    float v = acc[mt][nt][rr];
                    if (isFc) {
                        v += bv;
                        v = (v > 0.0f) ? v : 0.01f * v;
                        out[(size_t)m * FF + n] += v;
                    } else {
                        Hout[(size_t)m * FF + (n - FF)] = f2bf(v);
                    }
                }
            }
        }
    }
}

// ---------------------------------------------------------------------------
extern "C" void kernel_launch(void* const* d_in, const int* in_sizes, int n_in,
                              void* d_out, int out_size, void* d_ws, size_t ws_size,
                              hipStream_t stream) {
    const float* xa      = (const float*)d_in[0];
    const float* xv      = (const float*)d_in[1];
    const float* xt      = (const float*)d_in[2];
    const float* ew      = (const float*)d_in[3];
    const float* gcn_W   = (const float*)d_in[4];
    const float* gcn_b   = (const float*)d_in[5];
    const float* fc_W    = (const float*)d_in[6];
    const float* fc_b    = (const float*)d_in[7];
    const int*   eidx    = (const int*)d_in[8];
    const int E = in_sizes[8] / 2;
    const int* esrc = eidx;
    const int* edst = eidx + E;

    float* out = (float*)d_out;

    // workspace layout (64B aligned blocks)
    char* w = (char*)d_ws;
    int*          counts = (int*)         (w + 0);          // 24,000 (pad 24,064)
    float*        dinv   = (float*)       (w + 24064);      // 24,000 (pad 48,128)
    unsigned int* bucket = (unsigned int*)(w + 48128);      // 6000*128*4 = 3,072,000
    unsigned short* feat = (unsigned short*)(w + 3120128);  // 6,144,000
    unsigned short* H    = (unsigned short*)(w + 9264128);  // 6,144,000
    unsigned short* Wt   = (unsigned short*)(w + 15408128); // 2,097,152
    int*          pir    = (int*)         (w + 17505280);   // E*4 = 1,600,000

    hipMemsetAsync(counts, 0, 24000, stream);

    const int eblocks = (E + 255) / 256;
    prep<<<3256 + eblocks, 256, 0, stream>>>(xa, xv, xt, feat, out,
                                             gcn_W, fc_W, Wt, esrc, counts, pir, E);

    const int gxm = (NN + 63) / 64;   // 94
    const int ngemm0 = gxm * 8;       // 752
    // Wt slots: 0=gW0^T, 1=fW0^T, 2=gW1^T, 3=fW1^T (slots 1,2 contiguous)
    // merged: scatter (first, starts early) || H0 = feat0 @ gW0
    gemm0_scatter<<<eblocks + ngemm0, 256, 0, stream>>>(feat, Wt, H, NN, gxm, eblocks,
                                                        esrc, edst, ew, pir, bucket, E);
    rowsum_dinv<<<NN / 4, 256, 0, stream>>>(bucket, counts, dinv);

    // feat1 = relu(gcn@H0 + gb0)
    spmm_bias_relu<<<NN / 4, 256, 0, stream>>>(H, counts, bucket, dinv, gcn_b, feat);
    // out += leaky(feat1@fW0 + fb0)  AND  H1 = feat1 @ gW1   (fused)
    gemm_bf16<2><<<dim3(gxm, 16), 256, 0, stream>>>(feat, Wt + (size_t)FF * FF, fc_b, H, out, NN);
    // feat2 = relu(gcn@H1 + gb1)
    spmm_bias_relu<<<NN / 4, 256, 0, stream>>>(H, counts, bucket, dinv, gcn_b + FF, feat);
    // out += leaky(feat2@fW1 + fb1)
    gemm_bf16<1><<<dim3(gxm, 8), 256, 0, stream>>>(feat, Wt + (size_t)3 * FF * FF, fc_b + FF, nullptr, out, NN);
}